// Round 1
// baseline (387.806 us; speedup 1.0000x reference)
//
#include <hip/hip_runtime.h>

#define B_SZ 2
#define E_SZ 1024
#define C_SZ 128
#define R_REL 32
#define TS 64
#define TO 64

// Fused RESCAL: G = x x^T per batch (64x64 tile in registers), then
// out[b,s,r,o] = G[b,s,o] * R[r,s,o] streamed over r.
// Memory-bound: ~384 MiB mandatory HBM traffic -> ~61 us floor @ 6.3 TB/s.
__global__ __launch_bounds__(256, 2) void rescal_fused(
        const float* __restrict__ x,
        const float* __restrict__ R,
        float* __restrict__ out) {
    // +4 pad per row: breaks power-of-2 bank aliasing on the c-loop reads
    __shared__ float xs[TS][C_SZ + 4];
    __shared__ float xo[TO][C_SZ + 4];

    const int b  = blockIdx.z;
    const int s0 = blockIdx.y * TS;
    const int o0 = blockIdx.x * TO;
    const int tid = threadIdx.x;

    // ---- Phase 1: stage x tiles (rows are contiguous in global: c innermost)
    const float4* src_s = (const float4*)(x + (size_t)b * E_SZ * C_SZ + (size_t)s0 * C_SZ);
    const float4* src_o = (const float4*)(x + (size_t)b * E_SZ * C_SZ + (size_t)o0 * C_SZ);
    #pragma unroll
    for (int i = tid; i < TS * (C_SZ / 4); i += 256) {
        const int row = i >> 5;        // 32 float4 per row
        const int col = (i & 31) << 2; // float offset in row
        *(float4*)&xs[row][col] = src_s[i];
        *(float4*)&xo[row][col] = src_o[i];
    }
    __syncthreads();

    // ---- Phase 2: 64x64 G tile, 4x4 per thread, dot over C=128
    const int tx = tid & 15;   // o direction
    const int ty = tid >> 4;   // s direction
    const int si = ty << 2;
    const int oj = tx << 2;

    float acc[4][4];
    #pragma unroll
    for (int ii = 0; ii < 4; ++ii)
        #pragma unroll
        for (int jj = 0; jj < 4; ++jj) acc[ii][jj] = 0.f;

    #pragma unroll 4
    for (int c = 0; c < C_SZ; c += 4) {
        float4 a[4], bb[4];
        #pragma unroll
        for (int ii = 0; ii < 4; ++ii) a[ii]  = *(const float4*)&xs[si + ii][c];
        #pragma unroll
        for (int jj = 0; jj < 4; ++jj) bb[jj] = *(const float4*)&xo[oj + jj][c];
        #pragma unroll
        for (int ii = 0; ii < 4; ++ii) {
            #pragma unroll
            for (int jj = 0; jj < 4; ++jj) {
                acc[ii][jj] += a[ii].x * bb[jj].x + a[ii].y * bb[jj].y
                             + a[ii].z * bb[jj].z + a[ii].w * bb[jj].w;
            }
        }
    }

    // ---- Phase 3: stream over r, scale, write. Fully coalesced float4.
    const size_t out_base = ((size_t)b * E_SZ + (size_t)s0) * (size_t)(R_REL * E_SZ) + o0;
    #pragma unroll 1
    for (int r = 0; r < R_REL; ++r) {
        const float* Rp = R + (size_t)r * (E_SZ * E_SZ) + (size_t)s0 * E_SZ + o0;
        float* op = out + out_base + (size_t)r * E_SZ;
        #pragma unroll
        for (int ii = 0; ii < 4; ++ii) {
            const float4 rv = *(const float4*)(Rp + (size_t)(si + ii) * E_SZ + oj);
            float4 ov;
            ov.x = acc[ii][0] * rv.x;
            ov.y = acc[ii][1] * rv.y;
            ov.z = acc[ii][2] * rv.z;
            ov.w = acc[ii][3] * rv.w;
            *(float4*)(op + (size_t)(si + ii) * (R_REL * E_SZ) + oj) = ov;
        }
    }
}

extern "C" void kernel_launch(void* const* d_in, const int* in_sizes, int n_in,
                              void* d_out, int out_size, void* d_ws, size_t ws_size,
                              hipStream_t stream) {
    const float* x = (const float*)d_in[0];
    const float* R = (const float*)d_in[1];
    float* out = (float*)d_out;
    dim3 grid(E_SZ / TO, E_SZ / TS, B_SZ);
    rescal_fused<<<grid, 256, 0, stream>>>(x, R, out);
}